// Round 1
// baseline (304.007 us; speedup 1.0000x reference)
//
#include <hip/hip_runtime.h>
#include <math.h>

// y[b,t,d] = sum_{s<=t} x[b,s,d] * exp(-|decay[d]|*(t-s)) * cos(freq[d]*(t-s))
//          = Re(z[t]),  z[t] = r*z[t-1] + x[t],  r = exp(-|decay[d]|) * e^{i*freq[d]}
// Blocked scan over t: C chunks of length L = T/C.

#define D_DIM 1024

__global__ __launch_bounds__(256) void carry_kernel(
    const float* __restrict__ x, const float* __restrict__ decay,
    const float* __restrict__ freq, float2* __restrict__ zloc,
    int T, int L, int C) {
  const int c = blockIdx.x;          // chunk
  const int b = blockIdx.z;          // batch
  const int d = blockIdx.y * 512 + threadIdx.x * 2;  // 2 channels per thread

  float a0 = fabsf(decay[d]),     w0 = freq[d];
  float a1 = fabsf(decay[d + 1]), w1 = freq[d + 1];
  float e0 = expf(-a0), e1 = expf(-a1);
  float rr0 = e0 * cosf(w0), ri0 = e0 * sinf(w0);
  float rr1 = e1 * cosf(w1), ri1 = e1 * sinf(w1);

  const float2* xp =
      (const float2*)(x + ((size_t)b * T + (size_t)c * L) * D_DIM + d);
  const size_t stride = D_DIM / 2;

  float z0r = 0.f, z0i = 0.f, z1r = 0.f, z1i = 0.f;
  for (int t = 0; t < L; ++t) {
    float2 xv = xp[(size_t)t * stride];
    float n0r = fmaf(rr0, z0r, fmaf(-ri0, z0i, xv.x));
    float n0i = fmaf(rr0, z0i, ri0 * z0r);
    float n1r = fmaf(rr1, z1r, fmaf(-ri1, z1i, xv.y));
    float n1i = fmaf(rr1, z1i, ri1 * z1r);
    z0r = n0r; z0i = n0i; z1r = n1r; z1i = n1i;
  }
  size_t idx = ((size_t)b * C + c) * D_DIM + d;
  zloc[idx]     = make_float2(z0r, z0i);
  zloc[idx + 1] = make_float2(z1r, z1i);
}

// Per (b,d): Zin[0] = 0; Zin[c] = zloc[c-1] + r^L * Zin[c-1].
__global__ __launch_bounds__(256) void scan_kernel(
    const float* __restrict__ decay, const float* __restrict__ freq,
    const float2* __restrict__ zloc, float2* __restrict__ zin,
    int L, int C) {
  int g = blockIdx.x * blockDim.x + threadIdx.x;  // 0 .. B*D-1
  int b = g >> 10;
  int d = g & (D_DIM - 1);
  float a = fabsf(decay[d]);
  float w = freq[d];
  float fL = (float)L;
  float e = expf(-a * fL);
  float rLr = e * cosf(w * fL), rLi = e * sinf(w * fL);

  float zr = 0.f, zi = 0.f;
  size_t base = (size_t)b * C * D_DIM + d;
  zin[base] = make_float2(0.f, 0.f);
  for (int c = 1; c < C; ++c) {
    float2 zl = zloc[base + (size_t)(c - 1) * D_DIM];
    float nr = fmaf(rLr, zr, fmaf(-rLi, zi, zl.x));
    float ni = fmaf(rLr, zi, fmaf(rLi, zr, zl.y));
    zr = nr; zi = ni;
    zin[base + (size_t)c * D_DIM] = make_float2(zr, zi);
  }
}

__global__ __launch_bounds__(256) void final_kernel(
    const float* __restrict__ x, const float* __restrict__ decay,
    const float* __restrict__ freq, const float2* __restrict__ zin,
    float* __restrict__ y, int T, int L, int C) {
  const int c = blockIdx.x;
  const int b = blockIdx.z;
  const int d = blockIdx.y * 512 + threadIdx.x * 2;

  float a0 = fabsf(decay[d]),     w0 = freq[d];
  float a1 = fabsf(decay[d + 1]), w1 = freq[d + 1];
  float e0 = expf(-a0), e1 = expf(-a1);
  float rr0 = e0 * cosf(w0), ri0 = e0 * sinf(w0);
  float rr1 = e1 * cosf(w1), ri1 = e1 * sinf(w1);

  size_t zbase = ((size_t)b * C + c) * D_DIM + d;
  float2 s0 = zin[zbase], s1 = zin[zbase + 1];
  float z0r = s0.x, z0i = s0.y, z1r = s1.x, z1i = s1.y;

  const size_t off = ((size_t)b * T + (size_t)c * L) * D_DIM + d;
  const float2* xp = (const float2*)(x + off);
  float2* yp = (float2*)(y + off);
  const size_t stride = D_DIM / 2;

  for (int t = 0; t < L; ++t) {
    float2 xv = xp[(size_t)t * stride];
    float n0r = fmaf(rr0, z0r, fmaf(-ri0, z0i, xv.x));
    float n0i = fmaf(rr0, z0i, ri0 * z0r);
    float n1r = fmaf(rr1, z1r, fmaf(-ri1, z1i, xv.y));
    float n1i = fmaf(rr1, z1i, ri1 * z1r);
    z0r = n0r; z0i = n0i; z1r = n1r; z1i = n1i;
    yp[(size_t)t * stride] = make_float2(z0r, z1r);
  }
}

extern "C" void kernel_launch(void* const* d_in, const int* in_sizes, int n_in,
                              void* d_out, int out_size, void* d_ws, size_t ws_size,
                              hipStream_t stream) {
  const float* x     = (const float*)d_in[0];
  const float* decay = (const float*)d_in[1];
  const float* freq  = (const float*)d_in[2];
  float* y = (float*)d_out;

  const int B = 4, T = 8192;  // x: [B, T, D_DIM] per setup_inputs()

  // Workspace: zloc + zin, each B*C*D complex fp32 -> C * 64 KiB total.
  int C = 128;
  while (C > 1 && (size_t)C * (size_t)(2 * B * D_DIM * sizeof(float2)) > ws_size)
    C >>= 1;
  int L = T / C;

  float2* zloc = (float2*)d_ws;
  float2* zin  = zloc + (size_t)B * C * D_DIM;

  dim3 grid(C, D_DIM / 512, B);
  carry_kernel<<<grid, 256, 0, stream>>>(x, decay, freq, zloc, T, L, C);
  scan_kernel<<<(B * D_DIM) / 256, 256, 0, stream>>>(decay, freq, zloc, zin, L, C);
  final_kernel<<<grid, 256, 0, stream>>>(x, decay, freq, zin, y, T, L, C);
}

// Round 3
// 267.112 us; speedup vs baseline: 1.1381x; 1.1381x over previous
//
#include <hip/hip_runtime.h>
#include <math.h>

// y[b,t,d] = Re(z[t]),  z[t] = r*z[t-1] + x[t],  r = exp(-|decay[d]|) * e^{i*freq[d]}
// 2-pass blocked scan over t: C chunks of length L = T/C.
//   Pass 1 (carry):  per chunk, local end-state zloc from zero init (reads x once).
//   Pass 2 (final):  per chunk, Horner-combine zloc[0..c-1] with r^L powers to get
//                    the chunk's incoming state, then recompute chunk writing y.
//                    (zloc is 4 MiB -> L2/L3 resident; O(C^2) re-reads are cheap.)

#define D_DIM 1024

typedef float floatx4 __attribute__((ext_vector_type(4)));

__device__ __forceinline__ void load_r(const float* __restrict__ decay,
                                       const float* __restrict__ freq, int d,
                                       float* rr, float* ri, float* aa, float* ww) {
  float4 dv = *(const float4*)(decay + d);
  float4 fv = *(const float4*)(freq + d);
  float a[4] = {dv.x, dv.y, dv.z, dv.w};
  float w[4] = {fv.x, fv.y, fv.z, fv.w};
#pragma unroll
  for (int k = 0; k < 4; ++k) {
    float ak = fabsf(a[k]);
    float e = expf(-ak);
    rr[k] = e * cosf(w[k]);
    ri[k] = e * sinf(w[k]);
    aa[k] = ak;
    ww[k] = w[k];
  }
}

__global__ __launch_bounds__(256) void carry_kernel(
    const float* __restrict__ x, const float* __restrict__ decay,
    const float* __restrict__ freq, float2* __restrict__ zloc,
    int T, int L, int C) {
  const int c = blockIdx.x;
  const int b = blockIdx.y;
  const int d = threadIdx.x * 4;  // 4 channels per thread; block covers D=1024

  float rr[4], ri[4], aa[4], ww[4];
  load_r(decay, freq, d, rr, ri, aa, ww);

  const float4* xp =
      (const float4*)(x + ((size_t)b * T + (size_t)c * L) * D_DIM + d);
  const size_t stride = D_DIM / 4;

  float zr[4] = {0.f, 0.f, 0.f, 0.f}, zi[4] = {0.f, 0.f, 0.f, 0.f};
#pragma unroll 4
  for (int t = 0; t < L; ++t) {
    float4 xv = xp[(size_t)t * stride];
    float xs[4] = {xv.x, xv.y, xv.z, xv.w};
#pragma unroll
    for (int k = 0; k < 4; ++k) {
      float nr = fmaf(rr[k], zr[k], fmaf(-ri[k], zi[k], xs[k]));
      float ni = fmaf(rr[k], zi[k], ri[k] * zr[k]);
      zr[k] = nr;
      zi[k] = ni;
    }
  }

  float4* zp = (float4*)(zloc + ((size_t)b * C + c) * D_DIM + d);
  zp[0] = make_float4(zr[0], zi[0], zr[1], zi[1]);
  zp[1] = make_float4(zr[2], zi[2], zr[3], zi[3]);
}

__global__ __launch_bounds__(256) void final_kernel(
    const float* __restrict__ x, const float* __restrict__ decay,
    const float* __restrict__ freq, const float2* __restrict__ zloc,
    float* __restrict__ y, int T, int L, int C) {
  const int c = blockIdx.x;
  const int b = blockIdx.y;
  const int d = threadIdx.x * 4;

  float rr[4], ri[4], aa[4], ww[4];
  load_r(decay, freq, d, rr, ri, aa, ww);

  // r^L per channel
  float rLr[4], rLi[4];
  const float fL = (float)L;
#pragma unroll
  for (int k = 0; k < 4; ++k) {
    float e = expf(-aa[k] * fL);
    rLr[k] = e * cosf(ww[k] * fL);
    rLi[k] = e * sinf(ww[k] * fL);
  }

  // Horner: Zin = sum_{j<c} r^{L(c-1-j)} * zloc[j]
  float Zr[4] = {0.f, 0.f, 0.f, 0.f}, Zi[4] = {0.f, 0.f, 0.f, 0.f};
  const float2* zl = zloc + (size_t)b * C * D_DIM + d;
  for (int j = 0; j < c; ++j) {
    float4 v0 = *(const float4*)(zl + (size_t)j * D_DIM);
    float4 v1 = *(const float4*)(zl + (size_t)j * D_DIM + 2);
    float lr[4] = {v0.x, v0.z, v1.x, v1.z};
    float li[4] = {v0.y, v0.w, v1.y, v1.w};
#pragma unroll
    for (int k = 0; k < 4; ++k) {
      float nr = fmaf(rLr[k], Zr[k], fmaf(-rLi[k], Zi[k], lr[k]));
      float ni = fmaf(rLr[k], Zi[k], fmaf(rLi[k], Zr[k], li[k]));
      Zr[k] = nr;
      Zi[k] = ni;
    }
  }

  const size_t off = ((size_t)b * T + (size_t)c * L) * D_DIM + d;
  const float4* xp = (const float4*)(x + off);
  floatx4* yp = (floatx4*)(y + off);
  const size_t stride = D_DIM / 4;

  float zr[4] = {Zr[0], Zr[1], Zr[2], Zr[3]};
  float zi[4] = {Zi[0], Zi[1], Zi[2], Zi[3]};
#pragma unroll 4
  for (int t = 0; t < L; ++t) {
    float4 xv = xp[(size_t)t * stride];
    float xs[4] = {xv.x, xv.y, xv.z, xv.w};
#pragma unroll
    for (int k = 0; k < 4; ++k) {
      float nr = fmaf(rr[k], zr[k], fmaf(-ri[k], zi[k], xs[k]));
      float ni = fmaf(rr[k], zi[k], ri[k] * zr[k]);
      zr[k] = nr;
      zi[k] = ni;
    }
    // Non-temporal: keep x L3-resident instead of y streaming through.
    floatx4 out = {zr[0], zr[1], zr[2], zr[3]};
    __builtin_nontemporal_store(out, &yp[(size_t)t * stride]);
  }
}

extern "C" void kernel_launch(void* const* d_in, const int* in_sizes, int n_in,
                              void* d_out, int out_size, void* d_ws, size_t ws_size,
                              hipStream_t stream) {
  const float* x     = (const float*)d_in[0];
  const float* decay = (const float*)d_in[1];
  const float* freq  = (const float*)d_in[2];
  float* y = (float*)d_out;

  const int B = 4, T = 8192;  // x: [B, T, D_DIM]

  int C = 128;  // zloc = B*C*D*8 B = 4 MiB
  while (C > 1 && (size_t)B * C * D_DIM * sizeof(float2) > ws_size) C >>= 1;
  int L = T / C;

  float2* zloc = (float2*)d_ws;

  dim3 grid(C, B);
  carry_kernel<<<grid, 256, 0, stream>>>(x, decay, freq, zloc, T, L, C);
  final_kernel<<<grid, 256, 0, stream>>>(x, decay, freq, zloc, y, T, L, C);
}